// Round 10
// baseline (762.064 us; speedup 1.0000x reference)
//
#include <hip/hip_runtime.h>
#include <math.h>

// Problem constants (B=1)
#define L_Q     2048
#define KV_PREV 2048
#define KV_TOT  4096
#define DIM     2048
#define D_KV    512
#define NH      16
#define DH      32
#define HDh     512    // NH*DH
#define PAD     4104   // Sbf row stride (bf16)
#define KW      512    // per-wave KV slice (8 waves)

typedef short bf16x8 __attribute__((ext_vector_type(8)));
typedef short bf16x4 __attribute__((ext_vector_type(4)));
typedef float f32x4  __attribute__((ext_vector_type(4)));

__device__ inline short f2bf(float f) {   // RNE float -> bf16 bits
    unsigned u = __float_as_uint(f);
    u += 0x7fff + ((u >> 16) & 1);
    return (short)(u >> 16);
}
__device__ inline float bf2f(short s) {
    return __uint_as_float(((unsigned)(unsigned short)s) << 16);
}

// inv_freq[j] = 10000^(-j/16) = 10^(-j/4), precomputed in double.
__device__ __constant__ double c_invfreq[16] = {
    1.0, 0.5623413251903491, 0.31622776601683794, 0.17782794100389228,
    0.1, 0.05623413251903491, 0.03162277660168379, 0.017782794100389228,
    0.01, 0.005623413251903491, 0.0031622776601683794, 0.0017782794100389228,
    0.001, 0.0005623413251903491, 0.00031622776601683794, 0.00017782794100389227,
};

// ---------------------------------------------------------------- utilities
__global__ void cvt_bf16(const float* __restrict__ in, short* __restrict__ out, int n8) {
    int i = blockIdx.x * blockDim.x + threadIdx.x;
    if (i >= n8) return;
    float4 a = reinterpret_cast<const float4*>(in)[2 * i];
    float4 b = reinterpret_cast<const float4*>(in)[2 * i + 1];
    union { short s[8]; int4 v; } u;
    u.s[0] = f2bf(a.x); u.s[1] = f2bf(a.y); u.s[2] = f2bf(a.z); u.s[3] = f2bf(a.w);
    u.s[4] = f2bf(b.x); u.s[5] = f2bf(b.y); u.s[6] = f2bf(b.z); u.s[7] = f2bf(b.w);
    reinterpret_cast<int4*>(out)[i] = u.v;
}

__global__ void cvt_copy(const float* __restrict__ src, float* __restrict__ dst,
                         short* __restrict__ dbf, int n8) {
    int i = blockIdx.x * blockDim.x + threadIdx.x;
    if (i >= n8) return;
    float4 a = reinterpret_cast<const float4*>(src)[2 * i];
    float4 b = reinterpret_cast<const float4*>(src)[2 * i + 1];
    reinterpret_cast<float4*>(dst)[2 * i]     = a;
    reinterpret_cast<float4*>(dst)[2 * i + 1] = b;
    union { short s[8]; int4 v; } u;
    u.s[0] = f2bf(a.x); u.s[1] = f2bf(a.y); u.s[2] = f2bf(a.z); u.s[3] = f2bf(a.w);
    u.s[4] = f2bf(b.x); u.s[5] = f2bf(b.y); u.s[6] = f2bf(b.z); u.s[7] = f2bf(b.w);
    reinterpret_cast<int4*>(dbf)[i] = u.v;
}

// ALL five weight transposes in one launch.
__global__ __launch_bounds__(256) void tr_cvt_all(
        const float* __restrict__ W0, const float* __restrict__ W1,
        const float* __restrict__ W2, const float* __restrict__ W3,
        const float* __restrict__ W4,
        short* __restrict__ O0, short* __restrict__ O1, short* __restrict__ O2,
        short* __restrict__ O3, short* __restrict__ O4) {
    __shared__ float tile[32][33];
    int b = blockIdx.x;
    const float* in; short* out; int K, N;
    if (b < 1024)      { in = W0; out = O0; K = 2048; N = 512; }
    else if (b < 2048) { in = W1; out = O1; K = 2048; N = 512;  b -= 1024; }
    else if (b < 2304) { in = W2; out = O2; K = 512;  N = 512;  b -= 2048; }
    else if (b < 2560) { in = W3; out = O3; K = 512;  N = 512;  b -= 2304; }
    else               { in = W4; out = O4; K = 512;  N = 2048; b -= 2560; }
    int nkb = K / 32;
    int k0 = (b % nkb) * 32, n0 = (b / nkb) * 32;
    int c = threadIdx.x & 31, r0 = threadIdx.x >> 5;
    for (int r = r0; r < 32; r += 8)
        tile[r][c] = in[(size_t)(k0 + r) * N + n0 + c];
    __syncthreads();
    for (int r = r0; r < 32; r += 8)
        out[(size_t)(n0 + r) * K + k0 + c] = f2bf(tile[c][r]);
}

// v_bf: [KV][512] bf16 -> Vt: [NH][32][KV] bf16
__global__ __launch_bounds__(256) void vt_cvt(const short* __restrict__ v, short* __restrict__ vt) {
    __shared__ short tile[64][34];
    int h = blockIdx.y, kv0 = blockIdx.x * 64;
    int c = threadIdx.x & 31, r0 = threadIdx.x >> 5;
    for (int r = r0; r < 64; r += 8)
        tile[r][c] = v[(size_t)(kv0 + r) * HDh + h * DH + c];
    __syncthreads();
    int l = threadIdx.x & 63, wv = threadIdx.x >> 6;
    for (int d = wv; d < 32; d += 4)
        vt[((size_t)h * DH + d) * KV_TOT + kv0 + l] = tile[l][d];
}

// ------------------------------------------------- bf16 MFMA projection GEMM
__global__ __launch_bounds__(256) void gemm_bf16(const short* __restrict__ A,
        const short* __restrict__ Bt, const float* __restrict__ bias,
        float* __restrict__ C, short* __restrict__ Cbf, int rope,
        int M, int N, int K)
{
    int t = threadIdx.x, w = t >> 6, l = t & 63, lr = l & 15, lg = l >> 4;
    int m0 = blockIdx.y * 64 + w * 16;
    int n0 = blockIdx.x * 64;
    f32x4 acc[4] = {{0,0,0,0},{0,0,0,0},{0,0,0,0},{0,0,0,0}};
    const short* ap  = A  + (size_t)(m0 + lr) * K + lg * 8;
    const short* bp0 = Bt + (size_t)(n0 + lr) * K + lg * 8;
    #pragma unroll 2
    for (int k0 = 0; k0 < K; k0 += 32) {
        bf16x8 a = *reinterpret_cast<const bf16x8*>(ap + k0);
        #pragma unroll
        for (int j = 0; j < 4; ++j) {
            bf16x8 b = *reinterpret_cast<const bf16x8*>(bp0 + (size_t)j * 16 * K + k0);
            acc[j] = __builtin_amdgcn_mfma_f32_16x16x32_bf16(a, b, acc[j], 0, 0, 0);
        }
    }
    float bs[4];
    #pragma unroll
    for (int j = 0; j < 4; ++j) bs[j] = bias[n0 + j * 16 + lr];

    if (rope) {
        #pragma unroll
        for (int r = 0; r < 4; ++r) {
            int m = m0 + lg * 4 + r;
            float ang = (float)((double)m * c_invfreq[lr]);
            float cs = cosf(ang), sn = sinf(ang);
            size_t rb = (size_t)m * N + n0 + lr;
            float a1 = acc[0][r] + bs[0], a2 = acc[1][r] + bs[1];
            Cbf[rb]      = f2bf(a1 * cs - a2 * sn);
            Cbf[rb + 16] = f2bf(a1 * sn + a2 * cs);
            float b1 = acc[2][r] + bs[2], b2 = acc[3][r] + bs[3];
            Cbf[rb + 32] = f2bf(b1 * cs - b2 * sn);
            Cbf[rb + 48] = f2bf(b1 * sn + b2 * cs);
        }
        return;
    }
    #pragma unroll
    for (int j = 0; j < 4; ++j) {
        int n = n0 + j * 16 + lr;
        #pragma unroll
        for (int r = 0; r < 4; ++r) {
            float v = acc[j][r] + bs[j];
            size_t idx = (size_t)(m0 + lg * 4 + r) * N + n;
            if (C)   C[idx] = v;
            if (Cbf) Cbf[idx] = f2bf(v);
        }
    }
}

// ---------------- K1: QK^T + sums + masked PV + heads; bf16 scores -> scratch
// R9 structure; the ONLY global writes are the 268 MB bf16 scratch (linear
// rows) + heads (2 MB) + isu table. No f32 mega-streams here.
__global__ __launch_bounds__(512) void attn_core(const short* __restrict__ q,
        const short* __restrict__ kmat, const int* __restrict__ vlens,
        const short* __restrict__ Vt,
        short* __restrict__ scratch, float* __restrict__ isu_o,
        short* __restrict__ heads_bf)
{
    __shared__ short Sbf[16][PAD];       // 131,328 B
    __shared__ float red[8][16][2];
    __shared__ float Hst[8][64][8];      //  16,384 B
    int t = threadIdx.x, w = t >> 6, l = t & 63, lr = l & 15, lg = l >> 4;
    int h = blockIdx.y;
    int qrow = blockIdx.x * 16;
    int myq = qrow + lr;
    bf16x8 bQ = *reinterpret_cast<const bf16x8*>(q + (size_t)myq * HDh + h * DH + lg * 8);
    int vl = vlens[myq];
    const short* kp  = kmat + h * DH + lg * 8;
    const short* vp0 = Vt + ((size_t)h * DH + lr) * KV_TOT + lg * 8;
    const short* vp1 = vp0 + (size_t)16 * KV_TOT;
    const float sc = 0.17677669529663687f;
    const int kb = lg * 4;
    const int kw0 = w * KW;

    // Phase A: scores -> LDS bf16, online sums
    float su = 0.f, s2 = 0.f;
    bf16x8 a0 = *reinterpret_cast<const bf16x8*>(kp + (size_t)(kw0 + lr) * HDh);
    bf16x8 a1 = *reinterpret_cast<const bf16x8*>(kp + (size_t)(kw0 + 16 + lr) * HDh);
    for (int k0 = kw0; k0 < kw0 + KW; k0 += 32) {
        int kn = kw0 + ((k0 - kw0 + 32) & (KW - 1));
        bf16x8 a0n = *reinterpret_cast<const bf16x8*>(kp + (size_t)(kn + lr) * HDh);
        bf16x8 a1n = *reinterpret_cast<const bf16x8*>(kp + (size_t)(kn + 16 + lr) * HDh);
        f32x4 z4 = {0.f, 0.f, 0.f, 0.f};
        f32x4 s0 = __builtin_amdgcn_mfma_f32_16x16x32_bf16(a0, bQ, z4, 0, 0, 0);
        f32x4 s1 = __builtin_amdgcn_mfma_f32_16x16x32_bf16(a1, bQ, z4, 0, 0, 0);
        bf16x4 w0v, w1v;
        #pragma unroll
        for (int r = 0; r < 4; ++r) {
            float o0 = s0[r] * sc, o1 = s1[r] * sc;
            float e0 = __expf(o0), e1 = __expf(o1);
            su += e0 + e1;
            if (k0 + kb + r < vl)      s2 += e0;
            if (k0 + 16 + kb + r < vl) s2 += e1;
            w0v[r] = f2bf(o0);
            w1v[r] = f2bf(o1);
        }
        *reinterpret_cast<bf16x4*>(&Sbf[lr][k0 + kb])      = w0v;
        *reinterpret_cast<bf16x4*>(&Sbf[lr][k0 + 16 + kb]) = w1v;
        a0 = a0n; a1 = a1n;
    }
    su += __shfl_xor(su, 16, 64); su += __shfl_xor(su, 32, 64);
    s2 += __shfl_xor(s2, 16, 64); s2 += __shfl_xor(s2, 32, 64);
    if (lg == 0) { red[w][lr][0] = su; red[w][lr][1] = s2; }

    // Phase B1: unscaled masked PV from own Sbf slice
    f32x4 h0 = {0,0,0,0}, h1 = {0,0,0,0};
    for (int k0 = kw0; k0 < kw0 + KW; k0 += 32) {
        bf16x8 sv = *reinterpret_cast<const bf16x8*>(&Sbf[lr][k0 + lg * 8]);
        bf16x8 pa;
        #pragma unroll
        for (int j = 0; j < 8; ++j) {
            float e = __expf(bf2f(sv[j]));
            pa[j] = (k0 + lg * 8 + j < vl) ? f2bf(e) : (short)0;
        }
        bf16x8 b0 = *reinterpret_cast<const bf16x8*>(vp0 + k0);
        bf16x8 b1 = *reinterpret_cast<const bf16x8*>(vp1 + k0);
        h0 = __builtin_amdgcn_mfma_f32_16x16x32_bf16(pa, b0, h0, 0, 0, 0);
        h1 = __builtin_amdgcn_mfma_f32_16x16x32_bf16(pa, b1, h1, 0, 0, 0);
    }
    *reinterpret_cast<f32x4*>(&Hst[w][l][0]) = h0;
    *reinterpret_cast<f32x4*>(&Hst[w][l][4]) = h1;
    __syncthreads();

    // Phase B2: linear bf16 row writeout (2 rows per wave) + isu
    #pragma unroll
    for (int rr = 0; rr < 2; ++rr) {
        int r = 2 * w + rr;
        short* srow = scratch + ((size_t)h * L_Q + qrow + r) * KV_TOT;
        #pragma unroll
        for (int i = 0; i < 8; ++i) {
            int col = i * 512 + l * 8;
            *reinterpret_cast<int4*>(srow + col) =
                *reinterpret_cast<const int4*>(&Sbf[r][col]);
        }
        if (l == 0) {
            float sut = 0.f;
            #pragma unroll
            for (int ww = 0; ww < 8; ++ww) sut += red[ww][r][0];
            isu_o[(size_t)h * L_Q + qrow + r] = 1.f / sut;
        }
    }

    // heads: combine 8 partials, scale by is2
    if (w == 0) {
        f32x4 g0 = {0,0,0,0}, g1 = {0,0,0,0};
        #pragma unroll
        for (int ww = 0; ww < 8; ++ww) {
            g0 += *reinterpret_cast<const f32x4*>(&Hst[ww][l][0]);
            g1 += *reinterpret_cast<const f32x4*>(&Hst[ww][l][4]);
        }
        #pragma unroll
        for (int r = 0; r < 4; ++r) {
            int rq = lg * 4 + r;
            float s2t = 0.f;
            #pragma unroll
            for (int ww = 0; ww < 8; ++ww) s2t += red[ww][rq][1];
            float is2 = 1.f / s2t;
            size_t ho = (size_t)(qrow + rq) * HDh + h * DH + lr;
            heads_bf[ho]      = f2bf(g0[r] * is2);
            heads_bf[ho + 16] = f2bf(g1[r] * is2);
        }
    }
}

// ------------- pure streamers (fill-identical structure, single stream each)
__global__ __launch_bounds__(256) void expand_scores(const short* __restrict__ sb,
        float* __restrict__ scores, size_t n8)
{
    size_t i = (size_t)blockIdx.x * blockDim.x + threadIdx.x;
    size_t stride = (size_t)gridDim.x * blockDim.x;
    for (; i < n8; i += stride) {
        int4 v = reinterpret_cast<const int4*>(sb)[i];
        const short* sp = reinterpret_cast<const short*>(&v);
        f32x4 oA, oB;
        #pragma unroll
        for (int j = 0; j < 4; ++j) { oA[j] = bf2f(sp[j]); oB[j] = bf2f(sp[4 + j]); }
        reinterpret_cast<f32x4*>(scores)[2 * i]     = oA;
        reinterpret_cast<f32x4*>(scores)[2 * i + 1] = oB;
    }
}

__global__ __launch_bounds__(256) void expand_attn(const short* __restrict__ sb,
        const float* __restrict__ isu, float* __restrict__ attn, size_t n8)
{
    size_t i = (size_t)blockIdx.x * blockDim.x + threadIdx.x;
    size_t stride = (size_t)gridDim.x * blockDim.x;
    for (; i < n8; i += stride) {
        int4 v = reinterpret_cast<const int4*>(sb)[i];
        const short* sp = reinterpret_cast<const short*>(&v);
        float is = isu[i >> 9];   // 512 8-elem chunks per 4096-row
        f32x4 oA, oB;
        #pragma unroll
        for (int j = 0; j < 4; ++j) {
            oA[j] = __expf(bf2f(sp[j])) * is;
            oB[j] = __expf(bf2f(sp[4 + j])) * is;
        }
        reinterpret_cast<f32x4*>(attn)[2 * i]     = oA;
        reinterpret_cast<f32x4*>(attn)[2 * i + 1] = oB;
    }
}

// ------------------------------------------------------------------ launch
extern "C" void kernel_launch(void* const* d_in, const int* in_sizes, int n_in,
                              void* d_out, int out_size, void* d_ws, size_t ws_size,
                              hipStream_t stream) {
    const float* x       = (const float*)d_in[0];
    const float* z_cache = (const float*)d_in[1];
    const int*   vlens   = (const int*)  d_in[2];
    const float* W_lat   = (const float*)d_in[3];
    const float* b_lat   = (const float*)d_in[4];
    const float* W_q     = (const float*)d_in[5];
    const float* b_q     = (const float*)d_in[6];
    const float* W_k     = (const float*)d_in[7];
    const float* b_k     = (const float*)d_in[8];
    const float* W_v     = (const float*)d_in[9];
    const float* b_v     = (const float*)d_in[10];
    const float* W_o     = (const float*)d_in[11];
    const float* b_o     = (const float*)d_in[12];

    float* out        = (float*)d_out;
    float* out_output = out;                                    // (2048, 2048)
    float* out_z      = out_output + (size_t)L_Q * DIM;         // (4096, 512)
    float* out_attn   = out_z + (size_t)KV_TOT * D_KV;          // (16, 2048, 4096)
    float* out_scores = out_attn + (size_t)NH * L_Q * KV_TOT;   // (16, 2048, 4096)

    // ---- workspace layout (scratch first: 268 MB, then small blobs)
    short* scratch  = (short*)d_ws;                     // 16*2048*4096 bf16
    float* ws_isu   = (float*)(scratch + (size_t)NH * L_Q * KV_TOT);  // 32768 f32
    short* wsb      = (short*)(ws_isu + (size_t)NH * L_Q);
    short* x_bf     = wsb;                              // 2048*2048
    short* z_bf     = x_bf + (size_t)L_Q * DIM;         // 4096*512
    short* q_bf     = z_bf + (size_t)KV_TOT * D_KV;     // 2048*512
    short* k_bf     = q_bf + (size_t)L_Q * HDh;         // 4096*512
    short* v_bf     = k_bf + (size_t)KV_TOT * HDh;      // 4096*512
    short* Vt       = v_bf + (size_t)KV_TOT * HDh;      // 16*32*4096
    short* heads_bf = Vt + (size_t)NH * DH * KV_TOT;    // 2048*512
    short* Wt_lat   = heads_bf + (size_t)L_Q * HDh;     // 512*2048
    short* Wt_q     = Wt_lat + (size_t)D_KV * DIM;      // 512*2048
    short* Wt_k     = Wt_q + (size_t)HDh * DIM;         // 512*512
    short* Wt_v     = Wt_k + (size_t)HDh * D_KV;        // 512*512
    short* Wt_o     = Wt_v + (size_t)HDh * D_KV;        // 2048*512

    // ---- prep
    cvt_bf16<<<(L_Q * DIM / 8 + 255) / 256, 256, 0, stream>>>(x, x_bf, L_Q * DIM / 8);
    cvt_copy<<<(KV_PREV * D_KV / 8 + 255) / 256, 256, 0, stream>>>(
        z_cache, out_z, z_bf, KV_PREV * D_KV / 8);
    tr_cvt_all<<<3584, 256, 0, stream>>>(W_lat, W_q, W_k, W_v, W_o,
                                         Wt_lat, Wt_q, Wt_k, Wt_v, Wt_o);

    // ---- z = concat(z_cache, x @ W_latent + b_latent)
    gemm_bf16<<<dim3(D_KV / 64, L_Q / 64), 256, 0, stream>>>(
        x_bf, Wt_lat, b_lat, out_z + (size_t)KV_PREV * D_KV,
        z_bf + (size_t)KV_PREV * D_KV, 0, L_Q, D_KV, DIM);

    // ---- projections
    gemm_bf16<<<dim3(HDh / 64, L_Q / 64), 256, 0, stream>>>(
        x_bf, Wt_q, b_q, nullptr, q_bf, 1, L_Q, HDh, DIM);
    gemm_bf16<<<dim3(HDh / 64, KV_TOT / 64), 256, 0, stream>>>(
        z_bf, Wt_k, b_k, nullptr, k_bf, 1, KV_TOT, HDh, D_KV);
    gemm_bf16<<<dim3(HDh / 64, KV_TOT / 64), 256, 0, stream>>>(
        z_bf, Wt_v, b_v, nullptr, v_bf, 0, KV_TOT, HDh, D_KV);
    vt_cvt<<<dim3(KV_TOT / 64, NH), 256, 0, stream>>>(v_bf, Vt);

    // ---- K1: core attention (bf16 scratch + sums + heads)
    attn_core<<<dim3(L_Q / 16, NH), 512, 0, stream>>>(
        q_bf, k_bf, vlens, Vt, scratch, ws_isu, heads_bf);

    // ---- pure streamers: scratch -> f32 scores / attn
    size_t n8 = (size_t)NH * L_Q * KV_TOT / 8;
    expand_scores<<<4096, 256, 0, stream>>>(scratch, out_scores, n8);
    expand_attn<<<4096, 256, 0, stream>>>(scratch, ws_isu, out_attn, n8);

    // ---- output projection
    gemm_bf16<<<dim3(DIM / 64, L_Q / 64), 256, 0, stream>>>(
        heads_bf, Wt_o, b_o, out_output, nullptr, 0, L_Q, DIM, HDh);
}

// Round 11
// 523.694 us; speedup vs baseline: 1.4552x; 1.4552x over previous
//
#include <hip/hip_runtime.h>
#include <math.h>

// Problem constants (B=1)
#define L_Q     2048
#define KV_PREV 2048
#define KV_TOT  4096
#define DIM     2048
#define D_KV    512
#define NH      16
#define DH      32
#define HDh     512   // NH*DH
#define KC      256   // k-chunk staged in LDS before contiguous writeout
#define KQ      (KV_TOT / 4)   // per-wave KV quarter = 1024

typedef short bf16x8 __attribute__((ext_vector_type(8)));
typedef short bf16x4 __attribute__((ext_vector_type(4)));
typedef float f32x4  __attribute__((ext_vector_type(4)));

__device__ inline short f2bf(float f) {   // RNE float -> bf16 bits
    unsigned u = __float_as_uint(f);
    u += 0x7fff + ((u >> 16) & 1);
    return (short)(u >> 16);
}

// inv_freq[j] = 10000^(-j/16) = 10^(-j/4), precomputed in double.
__device__ __constant__ double c_invfreq[16] = {
    1.0, 0.5623413251903491, 0.31622776601683794, 0.17782794100389228,
    0.1, 0.05623413251903491, 0.03162277660168379, 0.017782794100389228,
    0.01, 0.005623413251903491, 0.0031622776601683794, 0.0017782794100389228,
    0.001, 0.0005623413251903491, 0.00031622776601683794, 0.00017782794100389227,
};

// ---------------------------------------------------------------- utilities
// copy f32 -> f32 AND convert to bf16 in one read
__global__ void cvt_copy(const float* __restrict__ src, float* __restrict__ dst,
                         short* __restrict__ dbf, int n8) {
    int i = blockIdx.x * blockDim.x + threadIdx.x;
    if (i >= n8) return;
    float4 a = reinterpret_cast<const float4*>(src)[2 * i];
    float4 b = reinterpret_cast<const float4*>(src)[2 * i + 1];
    reinterpret_cast<float4*>(dst)[2 * i]     = a;
    reinterpret_cast<float4*>(dst)[2 * i + 1] = b;
    union { short s[8]; int4 v; } u;
    u.s[0] = f2bf(a.x); u.s[1] = f2bf(a.y); u.s[2] = f2bf(a.z); u.s[3] = f2bf(a.w);
    u.s[4] = f2bf(b.x); u.s[5] = f2bf(b.y); u.s[6] = f2bf(b.z); u.s[7] = f2bf(b.w);
    reinterpret_cast<int4*>(dbf)[i] = u.v;
}

// ALL five weight transposes in one launch (verified R7/R9/R10).
__global__ __launch_bounds__(256) void tr_cvt_all(
        const float* __restrict__ W0, const float* __restrict__ W1,
        const float* __restrict__ W2, const float* __restrict__ W3,
        const float* __restrict__ W4,
        short* __restrict__ O0, short* __restrict__ O1, short* __restrict__ O2,
        short* __restrict__ O3, short* __restrict__ O4) {
    __shared__ float tile[32][33];
    int b = blockIdx.x;
    const float* in; short* out; int K, N;
    if (b < 1024)      { in = W0; out = O0; K = 2048; N = 512; }
    else if (b < 2048) { in = W1; out = O1; K = 2048; N = 512;  b -= 1024; }
    else if (b < 2304) { in = W2; out = O2; K = 512;  N = 512;  b -= 2048; }
    else if (b < 2560) { in = W3; out = O3; K = 512;  N = 512;  b -= 2304; }
    else               { in = W4; out = O4; K = 512;  N = 2048; b -= 2560; }
    int nkb = K / 32;
    int k0 = (b % nkb) * 32, n0 = (b / nkb) * 32;
    int c = threadIdx.x & 31, r0 = threadIdx.x >> 5;
    for (int r = r0; r < 32; r += 8)
        tile[r][c] = in[(size_t)(k0 + r) * N + n0 + c];
    __syncthreads();
    for (int r = r0; r < 32; r += 8)
        out[(size_t)(n0 + r) * K + k0 + c] = f2bf(tile[c][r]);
}

// v_bf: [KV][512] bf16 -> Vt: [NH][32][KV] bf16 (per-head transposed V)
__global__ __launch_bounds__(256) void vt_cvt(const short* __restrict__ v, short* __restrict__ vt) {
    __shared__ short tile[64][34];
    int h = blockIdx.y, kv0 = blockIdx.x * 64;
    int c = threadIdx.x & 31, r0 = threadIdx.x >> 5;
    for (int r = r0; r < 64; r += 8)
        tile[r][c] = v[(size_t)(kv0 + r) * HDh + h * DH + c];
    __syncthreads();
    int l = threadIdx.x & 63, wv = threadIdx.x >> 6;
    for (int d = wv; d < 32; d += 4)
        vt[((size_t)h * DH + d) * KV_TOT + kv0 + l] = tile[l][d];
}

// -------------------------------------------- generic single bf16 MFMA GEMM
// (used only for the output projection: heads_bf @ Wt_o -> out, N=2048)
__global__ __launch_bounds__(256) void gemm_bf16(const short* __restrict__ A,
        const short* __restrict__ Bt, const float* __restrict__ bias,
        float* __restrict__ C, int M, int N, int K)
{
    int t = threadIdx.x, w = t >> 6, l = t & 63, lr = l & 15, lg = l >> 4;
    int m0 = blockIdx.y * 64 + w * 16;
    int n0 = blockIdx.x * 64;
    f32x4 acc[4] = {{0,0,0,0},{0,0,0,0},{0,0,0,0},{0,0,0,0}};
    const short* ap  = A  + (size_t)(m0 + lr) * K + lg * 8;
    const short* bp0 = Bt + (size_t)(n0 + lr) * K + lg * 8;
    #pragma unroll 2
    for (int k0 = 0; k0 < K; k0 += 32) {
        bf16x8 a = *reinterpret_cast<const bf16x8*>(ap + k0);
        #pragma unroll
        for (int j = 0; j < 4; ++j) {
            bf16x8 b = *reinterpret_cast<const bf16x8*>(bp0 + (size_t)j * 16 * K + k0);
            acc[j] = __builtin_amdgcn_mfma_f32_16x16x32_bf16(a, b, acc[j], 0, 0, 0);
        }
    }
    #pragma unroll
    for (int j = 0; j < 4; ++j) {
        int n = n0 + j * 16 + lr;
        float bs = bias[n];
        #pragma unroll
        for (int r = 0; r < 4; ++r)
            C[(size_t)(m0 + lg * 4 + r) * N + n] = acc[j][r] + bs;
    }
}

// ------------------------- dual projection GEMM: two N=512 outputs, shared A
// A is f32 (Af) or bf16 (Ab). Output row stride fixed at 512. Per side:
// optional f32 C, optional bf16 Cbf, optional rope (writes Cbf only).
__global__ __launch_bounds__(256) void gemm_dual(
        const float* __restrict__ Af, const short* __restrict__ Ab,
        const short* __restrict__ Bt0, const float* __restrict__ bias0,
        float* __restrict__ C0f, short* __restrict__ C0bf, int rope0,
        const short* __restrict__ Bt1, const float* __restrict__ bias1,
        float* __restrict__ C1f, short* __restrict__ C1bf, int rope1,
        int M, int K)
{
    int t = threadIdx.x, w = t >> 6, l = t & 63, lr = l & 15, lg = l >> 4;
    int side = blockIdx.x >> 3;
    int n0 = (blockIdx.x & 7) * 64;
    int m0 = blockIdx.y * 64 + w * 16;
    const short* Bt;  const float* bias;  float* Cf;  short* Cbf;  int rope;
    if (side == 0) { Bt = Bt0; bias = bias0; Cf = C0f; Cbf = C0bf; rope = rope0; }
    else           { Bt = Bt1; bias = bias1; Cf = C1f; Cbf = C1bf; rope = rope1; }

    f32x4 acc[4] = {{0,0,0,0},{0,0,0,0},{0,0,0,0},{0,0,0,0}};
    const float* afp = Af ? Af + (size_t)(m0 + lr) * K + lg * 8 : nullptr;
    const short* abp = Ab ? Ab + (size_t)(m0 + lr) * K + lg * 8 : nullptr;
    const short* bp0 = Bt + (size_t)(n0 + lr) * K + lg * 8;
    for (int k0 = 0; k0 < K; k0 += 32) {
        bf16x8 a;
        if (Af) {
            float4 f0 = *reinterpret_cast<const float4*>(afp + k0);
            float4 f1 = *reinterpret_cast<const float4*>(afp + k0 + 4);
            a[0] = f2bf(f0.x); a[1] = f2bf(f0.y); a[2] = f2bf(f0.z); a[3] = f2bf(f0.w);
            a[4] = f2bf(f1.x); a[5] = f2bf(f1.y); a[6] = f2bf(f1.z); a[7] = f2bf(f1.w);
        } else {
            a = *reinterpret_cast<const bf16x8*>(abp + k0);
        }
        #pragma unroll
        for (int j = 0; j < 4; ++j) {
            bf16x8 b = *reinterpret_cast<const bf16x8*>(bp0 + (size_t)j * 16 * K + k0);
            acc[j] = __builtin_amdgcn_mfma_f32_16x16x32_bf16(a, b, acc[j], 0, 0, 0);
        }
    }
    float bs[4];
    #pragma unroll
    for (int j = 0; j < 4; ++j) bs[j] = bias[n0 + j * 16 + lr];

    if (rope) {
        #pragma unroll
        for (int r = 0; r < 4; ++r) {
            int m = m0 + lg * 4 + r;
            float ang = (float)((double)m * c_invfreq[lr]);
            float cs = cosf(ang), sn = sinf(ang);
            size_t rb = (size_t)m * 512 + n0 + lr;
            float a1 = acc[0][r] + bs[0], a2 = acc[1][r] + bs[1];
            Cbf[rb]      = f2bf(a1 * cs - a2 * sn);
            Cbf[rb + 16] = f2bf(a1 * sn + a2 * cs);
            float b1 = acc[2][r] + bs[2], b2 = acc[3][r] + bs[3];
            Cbf[rb + 32] = f2bf(b1 * cs - b2 * sn);
            Cbf[rb + 48] = f2bf(b1 * sn + b2 * cs);
        }
        return;
    }
    #pragma unroll
    for (int j = 0; j < 4; ++j) {
        int n = n0 + j * 16 + lr;
        #pragma unroll
        for (int r = 0; r < 4; ++r) {
            float v = acc[j][r] + bs[j];
            size_t idx = (size_t)(m0 + lg * 4 + r) * 512 + n;
            if (Cf)  Cf[idx]  = v;
            if (Cbf) Cbf[idx] = f2bf(v);
        }
    }
}

// ---------------------------------------- K1: scores + online softmax sums
// (R8 verbatim — best measured attention structure.)
__global__ __launch_bounds__(256) void scores_stats(const short* __restrict__ q,
        const short* __restrict__ kmat, const int* __restrict__ vlens,
        float* __restrict__ scores, float* __restrict__ isu_o, float* __restrict__ is2_o)
{
    __shared__ float Sl[4][16][KC + 4];   // 66.6 KB, wave-private tiles
    __shared__ float red[4][16][2];
    int t = threadIdx.x, w = t >> 6, l = t & 63, lr = l & 15, lg = l >> 4;
    int h = blockIdx.y;
    int qrow = blockIdx.x * 16;           // block owns 16 q-rows
    int myq = qrow + lr;
    bf16x8 bQ = *reinterpret_cast<const bf16x8*>(q + (size_t)myq * HDh + h * DH + lg * 8);
    int vl = vlens[myq];
    const short* kp = kmat + h * DH + lg * 8;
    const float sc = 0.17677669529663687f;  // 1/sqrt(32)
    float su = 0.f, s2 = 0.f;
    const int kb = lg * 4;
    const int kq0 = w * KQ;               // wave's KV quarter base

    bf16x8 a0 = *reinterpret_cast<const bf16x8*>(kp + (size_t)(kq0 + lr) * HDh);
    bf16x8 a1 = *reinterpret_cast<const bf16x8*>(kp + (size_t)(kq0 + 16 + lr) * HDh);
    for (int c = 0; c < KQ / KC; ++c) {   // 4 chunks of 256
        int kbase = kq0 + c * KC;
        #pragma unroll
        for (int kt = 0; kt < KC / 32; ++kt) {
            int k0 = kbase + kt * 32;
            int kn = kq0 + ((c * KC + kt * 32 + 32) & (KQ - 1));
            bf16x8 a0n = *reinterpret_cast<const bf16x8*>(kp + (size_t)(kn + lr) * HDh);
            bf16x8 a1n = *reinterpret_cast<const bf16x8*>(kp + (size_t)(kn + 16 + lr) * HDh);
            f32x4 z4 = {0.f, 0.f, 0.f, 0.f};
            f32x4 s0 = __builtin_amdgcn_mfma_f32_16x16x32_bf16(a0, bQ, z4, 0, 0, 0);
            f32x4 s1 = __builtin_amdgcn_mfma_f32_16x16x32_bf16(a1, bQ, z4, 0, 0, 0);
            f32x4 o0, o1;
            #pragma unroll
            for (int r = 0; r < 4; ++r) { o0[r] = s0[r] * sc; o1[r] = s1[r] * sc; }
            *reinterpret_cast<f32x4*>(&Sl[w][lr][kt * 32 + kb])      = o0;
            *reinterpret_cast<f32x4*>(&Sl[w][lr][kt * 32 + 16 + kb]) = o1;
            #pragma unroll
            for (int r = 0; r < 4; ++r) {
                float e0 = __expf(o0[r]), e1 = __expf(o1[r]);
                su += e0 + e1;
                if (k0 + kb + r < vl)      s2 += e0;
                if (k0 + 16 + kb + r < vl) s2 += e1;
            }
            a0 = a0n; a1 = a1n;
        }
        __builtin_amdgcn_s_barrier();
        #pragma unroll
        for (int r = 0; r < 16; ++r) {
            f32x4 v = *reinterpret_cast<const f32x4*>(&Sl[w][r][l * 4]);
            __builtin_nontemporal_store(v, reinterpret_cast<f32x4*>(
                scores + ((size_t)h * L_Q + qrow + r) * KV_TOT + kbase + l * 4));
        }
    }
    su += __shfl_xor(su, 16, 64); su += __shfl_xor(su, 32, 64);
    s2 += __shfl_xor(s2, 16, 64); s2 += __shfl_xor(s2, 32, 64);
    if (lg == 0) { red[w][lr][0] = su; red[w][lr][1] = s2; }
    __syncthreads();
    if (t < 16) {
        float sut = red[0][t][0] + red[1][t][0] + red[2][t][0] + red[3][t][0];
        float s2t = red[0][t][1] + red[1][t][1] + red[2][t][1] + red[3][t][1];
        size_t idx = (size_t)h * L_Q + qrow + t;
        isu_o[idx] = 1.f / sut;
        is2_o[idx] = 1.f / s2t;
    }
}

// --------------------- K2: recompute scores, write attn, masked PV (MFMA)
// (R8 verbatim.)
__global__ __launch_bounds__(256) void attn_pv(const short* __restrict__ q,
        const short* __restrict__ kmat, const int* __restrict__ vlens,
        const float* __restrict__ isu_i, const float* __restrict__ is2_i,
        const short* __restrict__ Vt,
        float* __restrict__ attn, short* __restrict__ heads_bf)
{
    __shared__ float Al[4][16][KC + 4];   // 66.6 KB
    __shared__ short Plds[4][16][72];     //  9.2 KB
    int t = threadIdx.x, w = t >> 6, l = t & 63, lr = l & 15, lg = l >> 4;
    int h = blockIdx.y;
    int qrow = blockIdx.x * 16;
    int myq = qrow + lr;
    bf16x8 bQ = *reinterpret_cast<const bf16x8*>(q + (size_t)myq * HDh + h * DH + lg * 8);
    int vl = vlens[myq];
    size_t sidx = (size_t)h * L_Q + myq;
    float isu = isu_i[sidx], is2 = is2_i[sidx];
    const short* kp  = kmat + h * DH + lg * 8;
    const short* vp0 = Vt + ((size_t)h * DH + lr) * KV_TOT + lg * 8;   // d = lr
    const short* vp1 = vp0 + (size_t)16 * KV_TOT;                      // d = 16+lr
    const float sc = 0.17677669529663687f;
    const int kb = lg * 4;
    const int kq0 = w * KQ;
    short* prow = &Plds[w][lr][0];
    f32x4 h0 = {0,0,0,0}, h1 = {0,0,0,0};

    for (int c = 0; c < KQ / KC; ++c) {
        int kbase = kq0 + c * KC;
        #pragma unroll
        for (int g = 0; g < 4; ++g) {
            #pragma unroll
            for (int kt = 0; kt < 4; ++kt) {
                int i = g * 4 + kt;
                bf16x8 aK = *reinterpret_cast<const bf16x8*>(
                    kp + (size_t)(kbase + i * 16 + lr) * HDh);
                f32x4 z4 = {0.f, 0.f, 0.f, 0.f};
                f32x4 s = __builtin_amdgcn_mfma_f32_16x16x32_bf16(aK, bQ, z4, 0, 0, 0);
                f32x4 oa;
                bf16x4 pb;
                #pragma unroll
                for (int r = 0; r < 4; ++r) {
                    float e = __expf(s[r] * sc);
                    oa[r] = e * isu;
                    pb[r] = (kbase + i * 16 + kb + r < vl) ? f2bf(e * is2) : (short)0;
                }
                *reinterpret_cast<f32x4*>(&Al[w][lr][i * 16 + kb]) = oa;
                *reinterpret_cast<bf16x4*>(prow + kt * 16 + kb) = pb;
            }
            #pragma unroll
            for (int kbl = 0; kbl < 2; ++kbl) {
                int kv = kbase + g * 64 + kbl * 32;
                bf16x8 pa = *reinterpret_cast<const bf16x8*>(prow + kbl * 32 + lg * 8);
                bf16x8 b0 = *reinterpret_cast<const bf16x8*>(vp0 + kv);
                bf16x8 b1 = *reinterpret_cast<const bf16x8*>(vp1 + kv);
                h0 = __builtin_amdgcn_mfma_f32_16x16x32_bf16(pa, b0, h0, 0, 0, 0);
                h1 = __builtin_amdgcn_mfma_f32_16x16x32_bf16(pa, b1, h1, 0, 0, 0);
            }
        }
        __builtin_amdgcn_s_barrier();
        #pragma unroll
        for (int r = 0; r < 16; ++r) {
            f32x4 v = *reinterpret_cast<const f32x4*>(&Al[w][r][l * 4]);
            __builtin_nontemporal_store(v, reinterpret_cast<f32x4*>(
                attn + ((size_t)h * L_Q + qrow + r) * KV_TOT + kbase + l * 4));
        }
    }
    __syncthreads();
    float* hst = &Al[0][0][0];
    if (w > 0) {
        *reinterpret_cast<f32x4*>(&hst[((w - 1) * 64 + l) * 8])     = h0;
        *reinterpret_cast<f32x4*>(&hst[((w - 1) * 64 + l) * 8 + 4]) = h1;
    }
    __syncthreads();
    if (w == 0) {
        #pragma unroll
        for (int ww = 0; ww < 3; ++ww) {
            f32x4 g0 = *reinterpret_cast<const f32x4*>(&hst[(ww * 64 + l) * 8]);
            f32x4 g1 = *reinterpret_cast<const f32x4*>(&hst[(ww * 64 + l) * 8 + 4]);
            h0 += g0; h1 += g1;
        }
        #pragma unroll
        for (int r = 0; r < 4; ++r) {
            size_t ho = (size_t)(qrow + lg * 4 + r) * HDh + h * DH + lr;
            heads_bf[ho]      = f2bf(h0[r]);
            heads_bf[ho + 16] = f2bf(h1[r]);
        }
    }
}

// ------------------------------------------------------------------ launch
extern "C" void kernel_launch(void* const* d_in, const int* in_sizes, int n_in,
                              void* d_out, int out_size, void* d_ws, size_t ws_size,
                              hipStream_t stream) {
    const float* x       = (const float*)d_in[0];
    const float* z_cache = (const float*)d_in[1];
    const int*   vlens   = (const int*)  d_in[2];
    const float* W_lat   = (const float*)d_in[3];
    const float* b_lat   = (const float*)d_in[4];
    const float* W_q     = (const float*)d_in[5];
    const float* b_q     = (const float*)d_in[6];
    const float* W_k     = (const float*)d_in[7];
    const float* b_k     = (const float*)d_in[8];
    const float* W_v     = (const float*)d_in[9];
    const float* b_v     = (const float*)d_in[10];
    const float* W_o     = (const float*)d_in[11];
    const float* b_o     = (const float*)d_in[12];

    float* out        = (float*)d_out;
    float* out_output = out;                                    // (2048, 2048)
    float* out_z      = out_output + (size_t)L_Q * DIM;         // (4096, 512)
    float* out_attn   = out_z + (size_t)KV_TOT * D_KV;          // (16, 2048, 4096)
    float* out_scores = out_attn + (size_t)NH * L_Q * KV_TOT;   // (16, 2048, 4096)

    // ---- workspace layout
    float* wf     = (float*)d_ws;
    float* ws_isu = wf;                               // 16*2048
    float* ws_is2 = ws_isu + (size_t)NH * L_Q;        // 16*2048
    short* wsb      = (short*)(ws_is2 + (size_t)NH * L_Q);
    short* z_bf     = wsb;                              // 4096*512
    short* q_bf     = z_bf + (size_t)KV_TOT * D_KV;     // 2048*512
    short* k_bf     = q_bf + (size_t)L_Q * HDh;         // 4096*512
    short* v_bf     = k_bf + (size_t)KV_TOT * HDh;      // 4096*512
    short* Vt       = v_bf + (size_t)KV_TOT * HDh;      // 16*32*4096
    short* heads_bf = Vt + (size_t)NH * DH * KV_TOT;    // 2048*512
    short* Wt_lat   = heads_bf + (size_t)L_Q * HDh;     // 512*2048
    short* Wt_q     = Wt_lat + (size_t)D_KV * DIM;      // 512*2048
    short* Wt_k     = Wt_q + (size_t)HDh * DIM;         // 512*512
    short* Wt_v     = Wt_k + (size_t)HDh * D_KV;        // 512*512
    short* Wt_o     = Wt_v + (size_t)HDh * D_KV;        // 2048*512

    // ---- prep
    cvt_copy<<<(KV_PREV * D_KV / 8 + 255) / 256, 256, 0, stream>>>(
        z_cache, out_z, z_bf, KV_PREV * D_KV / 8);
    tr_cvt_all<<<3584, 256, 0, stream>>>(W_lat, W_q, W_k, W_v, W_o,
                                         Wt_lat, Wt_q, Wt_k, Wt_v, Wt_o);

    // ---- fused lat+q projections (A = f32 x, converted in-kernel)
    gemm_dual<<<dim3(16, L_Q / 64), 256, 0, stream>>>(
        x, nullptr,
        Wt_lat, b_lat, out_z + (size_t)KV_PREV * D_KV, z_bf + (size_t)KV_PREV * D_KV, 0,
        Wt_q, b_q, nullptr, q_bf, 1,
        L_Q, DIM);

    // ---- fused k+v projections (A = z_bf)
    gemm_dual<<<dim3(16, KV_TOT / 64), 256, 0, stream>>>(
        nullptr, z_bf,
        Wt_k, b_k, nullptr, k_bf, 1,
        Wt_v, b_v, nullptr, v_bf, 0,
        KV_TOT, D_KV);
    vt_cvt<<<dim3(KV_TOT / 64, NH), 256, 0, stream>>>(v_bf, Vt);

    // ---- K1: scores + softmax sums (block = 16 q-rows, waves split KV)
    scores_stats<<<dim3(L_Q / 16, NH), 256, 0, stream>>>(
        q_bf, k_bf, vlens, out_scores, ws_isu, ws_is2);

    // ---- K2: attn weights (recomputed scores) + PV
    attn_pv<<<dim3(L_Q / 16, NH), 256, 0, stream>>>(
        q_bf, k_bf, vlens, ws_isu, ws_is2, Vt, out_attn, heads_bf);

    // ---- output projection
    gemm_bf16<<<dim3(DIM / 64, L_Q / 64), 256, 0, stream>>>(
        heads_bf, Wt_o, b_o, out_output, L_Q, DIM, HDh);
}